// Round 4
// baseline (213.784 us; speedup 1.0000x reference)
//
#include <hip/hip_runtime.h>
#include <math.h>

#define NB 1024
static constexpr float BN_INV = 0.99999500003749975f; // 1/sqrt(1+1e-5)

typedef __attribute__((ext_vector_type(8))) short short8;
typedef __attribute__((ext_vector_type(4))) float f32x4;

__device__ inline short f2bf(float f) {
  union { float f; unsigned u; } v;
  v.f = f;
  unsigned u = v.u;
  u += 0x7fff + ((u >> 16) & 1); // RNE
  return (short)(u >> 16);
}

// ---------------- prepack: conv2/conv3 weights -> MFMA A-frag bf16, BN fold,
// fr1 weights -> plain bf16 [512][2048] ------------------------------------
__global__ void k_prepack(const float* __restrict__ c2w, const float* __restrict__ c2b,
                          const float* __restrict__ g2, const float* __restrict__ be2,
                          const float* __restrict__ c3w, const float* __restrict__ c3b,
                          const float* __restrict__ g3, const float* __restrict__ be3,
                          const float* __restrict__ fr1w,
                          short* __restrict__ wp2, short* __restrict__ wp3,
                          float* __restrict__ scsh, short* __restrict__ wfr1) {
  int i = blockIdx.x * 256 + threadIdx.x;
  int stride = gridDim.x * 256;
  for (int e = i; e < 18432; e += stride) {
    int j = e & 7, lane = (e >> 3) & 63, ct = (e >> 9) & 3, off = e >> 11;
    int co = ct * 16 + (lane & 15), ci = (lane >> 4) * 8 + j;
    wp2[e] = f2bf(c2w[(co * 32 + ci) * 9 + off]);
  }
  for (int e = i; e < 73728; e += stride) {
    int j = e & 7, lane = (e >> 3) & 63, ct = (e >> 9) & 7, oh = e >> 12;
    int half = oh & 1, off = oh >> 1;
    int co = ct * 16 + (lane & 15), ci = half * 32 + (lane >> 4) * 8 + j;
    wp3[e] = f2bf(c3w[(co * 64 + ci) * 9 + off]);
  }
  for (int e = i; e < 524288; e += stride) {
    float2 f = ((const float2*)fr1w)[e];
    unsigned lo = (unsigned)(unsigned short)f2bf(f.x);
    unsigned hi = (unsigned)(unsigned short)f2bf(f.y);
    ((unsigned*)wfr1)[e] = (hi << 16) | lo;
  }
  if (i < 64) {
    float sc = g2[i] * BN_INV;
    scsh[i] = sc;
    scsh[64 + i] = sc * c2b[i] + be2[i];
  } else if (i < 192) {
    int c = i - 64;
    float sc = g3[c] * BN_INV;
    scsh[128 + c] = sc;
    scsh[256 + c] = sc * c3b[c] + be3[c];
  }
}

// ---------------- fused conv1+conv2+conv3 (one sample per block) ------------
// conv1: f32 VALU, 3->32, 32x32, BN+ReLU+maxpool -> bf16 NHWC in LDS inT
// conv2: MFMA 32->64, BN+ReLU+maxpool -> bf16 NHWC in LDS inT3
// conv3: MFMA 64->128, BN+ReLU+avgpool -> bf16 out3 [B,2048]
__global__ __launch_bounds__(256) void k_conv123(
    const float* __restrict__ x, const float* __restrict__ c1w,
    const float* __restrict__ c1b, const float* __restrict__ g1,
    const float* __restrict__ be1, const short* __restrict__ wp2,
    const short* __restrict__ wp3, const float* __restrict__ scsh,
    short* __restrict__ out3) {
  __shared__ float tile[3 * 34 * 34];               // 13.9 KB (conv1 input, f32)
  __shared__ __align__(16) short inT[18 * 18 * 40]; // 25.9 KB [y][x][ci40]
  __shared__ __align__(16) short inT3[10 * 10 * 72];// 14.4 KB [y][x][ci72]
  const int b = blockIdx.x;
  const int tid = threadIdx.x;
  const int w = tid >> 6, lane = tid & 63, q = lane >> 4, n = lane & 15;

  // zero inT + inT3 (halo correctness); interior of inT overwritten by conv1
  {
    int4 z = {0, 0, 0, 0};
    for (int i = tid; i < 1620; i += 256) ((int4*)inT)[i] = z;
    for (int i = tid; i < 900; i += 256) ((int4*)inT3)[i] = z;
  }
  // stage x tile f32 with halo
  const float* xb = x + (size_t)b * 3072;
  for (int i = tid; i < 3 * 34 * 34; i += 256) {
    int c = i / 1156;
    int rem = i - c * 1156;
    int r = rem / 34;
    int col = rem - r * 34;
    int iy = r - 1, ix = col - 1;
    float v = 0.f;
    if (iy >= 0 && iy < 32 && ix >= 0 && ix < 32)
      v = xb[(c * 32 + iy) * 32 + ix];
    tile[i] = v;
  }
  __syncthreads();

  // ---- conv1 phase (per-thread: one pooled px, all 32 co) ----
  {
    const int tx = tid & 15, ty = tid >> 4;
    float win[3][4][4];
#pragma unroll
    for (int c = 0; c < 3; ++c)
#pragma unroll
      for (int r = 0; r < 4; ++r)
#pragma unroll
        for (int cc = 0; cc < 4; ++cc)
          win[c][r][cc] = tile[c * 1156 + (2 * ty + r) * 34 + 2 * tx + cc];

    unsigned pk[16];
#pragma unroll
    for (int co = 0; co < 32; ++co) {
      const float* wp = c1w + co * 27;
      float a00 = 0.f, a01 = 0.f, a10 = 0.f, a11 = 0.f;
#pragma unroll
      for (int c = 0; c < 3; ++c)
#pragma unroll
        for (int ky = 0; ky < 3; ++ky)
#pragma unroll
          for (int kx = 0; kx < 3; ++kx) {
            float wv = wp[c * 9 + ky * 3 + kx];
            a00 = fmaf(win[c][ky][kx], wv, a00);
            a01 = fmaf(win[c][ky][kx + 1], wv, a01);
            a10 = fmaf(win[c][ky + 1][kx], wv, a10);
            a11 = fmaf(win[c][ky + 1][kx + 1], wv, a11);
          }
      float gg = g1[co] * BN_INV, bt = be1[co], bs = c1b[co];
      float v0 = fmaxf(fmaf(gg, a00 + bs, bt), 0.f);
      float v1 = fmaxf(fmaf(gg, a01 + bs, bt), 0.f);
      float v2 = fmaxf(fmaf(gg, a10 + bs, bt), 0.f);
      float v3 = fmaxf(fmaf(gg, a11 + bs, bt), 0.f);
      float m = fmaxf(fmaxf(v0, v1), fmaxf(v2, v3));
      unsigned h = (unsigned)(unsigned short)f2bf(m);
      if (co & 1)
        pk[co >> 1] |= h << 16;
      else
        pk[co >> 1] = h;
    }
    short* dst = &inT[((ty + 1) * 18 + (tx + 1)) * 40];
#pragma unroll
    for (int i = 0; i < 4; ++i) {
      int4 v;
      v.x = (int)pk[4 * i + 0];
      v.y = (int)pk[4 * i + 1];
      v.z = (int)pk[4 * i + 2];
      v.w = (int)pk[4 * i + 3];
      ((int4*)dst)[i] = v;
    }
  }
  __syncthreads();

  // ---- conv2 phase (MFMA), epilogue -> inT3 ----
  {
    const short8* wv = (const short8*)wp2;
    f32x4 acc[4][4]; // [t][ct]
#pragma unroll
    for (int t = 0; t < 4; ++t)
#pragma unroll
      for (int ct = 0; ct < 4; ++ct) acc[t][ct] = (f32x4)0.f;

#pragma unroll
    for (int off = 0; off < 9; ++off) {
      const int ky = off / 3, kx = off % 3;
      short8 a[4];
#pragma unroll
      for (int ct = 0; ct < 4; ++ct) a[ct] = wv[(off * 4 + ct) * 64 + lane];
#pragma unroll
      for (int t = 0; t < 4; ++t) {
        int y = 4 * w + t;
        short8 bf = *(const short8*)&inT[((y + ky) * 18 + (n + kx)) * 40 + q * 8];
#pragma unroll
        for (int ct = 0; ct < 4; ++ct)
          acc[t][ct] = __builtin_amdgcn_mfma_f32_16x16x32_bf16(a[ct], bf,
                                                               acc[t][ct], 0, 0, 0);
      }
    }

    const float* sc2 = scsh;
    const float* sh2 = scsh + 64;
#pragma unroll
    for (int ct = 0; ct < 4; ++ct) {
      float vm[4][4];
#pragma unroll
      for (int t = 0; t < 4; ++t)
#pragma unroll
        for (int r = 0; r < 4; ++r) {
          int co = ct * 16 + q * 4 + r;
          float v = fmaf(sc2[co], acc[t][ct][r], sh2[co]);
          v = fmaxf(v, 0.f);
          vm[t][r] = fmaxf(v, __shfl_xor(v, 1));
        }
#pragma unroll
      for (int pp = 0; pp < 2; ++pp) {
        short4 s4;
#pragma unroll
        for (int r = 0; r < 4; ++r) {
          float m = fmaxf(vm[2 * pp][r], vm[2 * pp + 1][r]);
          ((short*)&s4)[r] = f2bf(m);
        }
        if ((n & 1) == 0) {
          int y = 2 * w + pp, xx = n >> 1;
          *(short4*)&inT3[((y + 1) * 10 + (xx + 1)) * 72 + ct * 16 + q * 4] = s4;
        }
      }
    }
  }
  __syncthreads();

  // ---- conv3 phase (MFMA), epilogue -> global bf16 [B,2048] ----
  {
    const short8* wv = (const short8*)wp3;
    f32x4 acc[4][2]; // [c][tt]
#pragma unroll
    for (int c = 0; c < 4; ++c)
#pragma unroll
      for (int tt = 0; tt < 2; ++tt) acc[c][tt] = (f32x4)0.f;

    const int ct0 = (w >> 1) * 4;
    const int t0 = (w & 1) * 2;
#pragma unroll
    for (int off = 0; off < 9; ++off) {
      const int ky = off / 3, kx = off % 3;
#pragma unroll
      for (int half = 0; half < 2; ++half) {
        short8 a[4];
#pragma unroll
        for (int c = 0; c < 4; ++c)
          a[c] = wv[((off * 2 + half) * 8 + ct0 + c) * 64 + lane];
#pragma unroll
        for (int tt = 0; tt < 2; ++tt) {
          int y = 2 * (t0 + tt) + (n >> 3), xx = n & 7;
          short8 bf = *(const short8*)&inT3[((y + ky) * 10 + (xx + kx)) * 72 +
                                            half * 32 + q * 8];
#pragma unroll
          for (int c = 0; c < 4; ++c)
            acc[c][tt] = __builtin_amdgcn_mfma_f32_16x16x32_bf16(a[c], bf,
                                                                 acc[c][tt], 0, 0, 0);
        }
      }
    }

    const float* sc3 = scsh + 128;
    const float* sh3 = scsh + 256;
#pragma unroll
    for (int c = 0; c < 4; ++c) {
      int ct = ct0 + c;
#pragma unroll
      for (int tt = 0; tt < 2; ++tt) {
        int t = t0 + tt;
#pragma unroll
        for (int r = 0; r < 4; ++r) {
          int co = ct * 16 + q * 4 + r;
          float v = fmaf(sc3[co], acc[c][tt][r], sh3[co]);
          v = fmaxf(v, 0.f);
          float s = v + __shfl_xor(v, 1);
          s += __shfl_xor(s, 8);
          if ((n & 9) == 0)
            out3[(size_t)b * 2048 + co * 16 + t * 4 + (n >> 1)] = f2bf(s * 0.25f);
        }
      }
    }
  }
}

// ---------------- fr1 (MFMA): [1024,2048]bf16 x [512,2048]bf16^T +bias,ReLU ->
// f32 [1024,512]. 32x32 tile/block, grid 32x16=512 blocks, BK=64. -------------
__global__ __launch_bounds__(256) void k_fr1m(
    const short* __restrict__ A, const short* __restrict__ W,
    const float* __restrict__ bias, float* __restrict__ C) {
  __shared__ __align__(16) short As[32 * 72];
  __shared__ __align__(16) short Bs[32 * 72];
  const int m0 = blockIdx.x * 32;
  const int n0 = blockIdx.y * 32;
  const int tid = threadIdx.x;
  const int w = tid >> 6, lane = tid & 63, q = lane >> 4, n = lane & 15;
  const int mt = w >> 1, nt = w & 1;
  const int srow = tid >> 3, sc = tid & 7;

  f32x4 acc = (f32x4)0.f;
  const short* Ab = A + (size_t)(m0 + srow) * 2048 + sc * 8;
  const short* Wb = W + (size_t)(n0 + srow) * 2048 + sc * 8;

  for (int k0 = 0; k0 < 2048; k0 += 64) {
    short8 av = *(const short8*)(Ab + k0);
    short8 bv = *(const short8*)(Wb + k0);
    __syncthreads();
    *(short8*)&As[srow * 72 + sc * 8] = av;
    *(short8*)&Bs[srow * 72 + sc * 8] = bv;
    __syncthreads();
#pragma unroll
    for (int kk = 0; kk < 2; ++kk) {
      short8 bfrag = *(const short8*)&Bs[(nt * 16 + n) * 72 + kk * 32 + q * 8];
      short8 afrag = *(const short8*)&As[(mt * 16 + n) * 72 + kk * 32 + q * 8];
      acc = __builtin_amdgcn_mfma_f32_16x16x32_bf16(afrag, bfrag, acc, 0, 0, 0);
    }
  }
#pragma unroll
  for (int r = 0; r < 4; ++r) {
    int m = m0 + mt * 16 + q * 4 + r;
    int nn = n0 + nt * 16 + n;
    C[(size_t)m * 512 + nn] = fmaxf(acc[r] + bias[nn], 0.f);
  }
}

// ---------------- tail: fr2 + softmax + quantum + head; 4 samples/block -----
__global__ __launch_bounds__(256) void k_tail4(
    const float* __restrict__ H, const float* __restrict__ W2,
    const float* __restrict__ b2, const float* __restrict__ qw,
    const float* __restrict__ h1w, const float* __restrict__ h1b,
    const float* __restrict__ bg, const float* __restrict__ bb,
    const float* __restrict__ h2w, const float* __restrict__ h2b,
    float* __restrict__ out) {
  __shared__ float hbuf[4][512];
  __shared__ float ybuf[4][128];
  const int wv4 = threadIdx.x >> 6;
  const int lane = threadIdx.x & 63;
  const int b = blockIdx.x * 4 + wv4;
  const float* hrow = H + (size_t)b * 512;
  *(float4*)&hbuf[wv4][lane * 4] = *(const float4*)&hrow[lane * 4];
  *(float4*)&hbuf[wv4][256 + lane * 4] = *(const float4*)&hrow[256 + lane * 4];
  __syncthreads();

  const int j = lane & 15;
  const int grpk = lane >> 4;
  float partial = 0.f;
  const float* wrow = W2 + j * 512 + grpk * 128;
  const float* hb = hbuf[wv4] + grpk * 128;
#pragma unroll
  for (int k = 0; k < 128; k += 4) {
    float4 wvv = *(const float4*)&wrow[k];
    partial = fmaf(wvv.x, hb[k + 0], partial);
    partial = fmaf(wvv.y, hb[k + 1], partial);
    partial = fmaf(wvv.z, hb[k + 2], partial);
    partial = fmaf(wvv.w, hb[k + 3], partial);
  }
  partial += __shfl_xor(partial, 16);
  partial += __shfl_xor(partial, 32);
  float logit = partial + b2[j];

  float m = logit;
#pragma unroll
  for (int d = 1; d < 16; d <<= 1) m = fmaxf(m, __shfl_xor(m, d));
  float e = expf(logit - m);
  float s = e;
#pragma unroll
  for (int d = 1; d < 16; d <<= 1) s += __shfl_xor(s, d);
  float p = e / s;

  float n2 = p * p;
#pragma unroll
  for (int d = 1; d < 16; d <<= 1) n2 += __shfl_xor(n2, d);
  float amp = p / sqrtf(n2);
  float re = amp, im = 0.f;

#pragma unroll
  for (int l = 0; l < 2; ++l) {
#pragma unroll
    for (int q = 0; q < 4; ++q) {
      float th = qw[l * 4 + q] * 0.5f;
      float c = cosf(th), sn = sinf(th);
      int mask = 1 << (3 - q);
      float pre = __shfl_xor(re, mask);
      float pim = __shfl_xor(im, mask);
      float nre = fmaf(c, re, sn * pim);
      float nim = fmaf(c, im, -sn * pre);
      re = nre;
      im = nim;
    }
    int src = j;
    if (src & 1) src ^= 8;
    if (src & 2) src ^= 1;
    if (src & 4) src ^= 2;
    if (src & 8) src ^= 4;
    int srclane = (lane & 48) | src;
    re = __shfl(re, srclane);
    im = __shfl(im, srclane);
  }

  float prob = re * re + im * im;
  float qv[4];
#pragma unroll
  for (int w = 0; w < 4; ++w) {
    float sgn = ((j >> (3 - w)) & 1) ? -1.f : 1.f;
    float cwv = prob * sgn;
    cwv += __shfl_xor(cwv, 1);
    cwv += __shfl_xor(cwv, 2);
    cwv += __shfl_xor(cwv, 4);
    cwv += __shfl_xor(cwv, 8);
    qv[w] = cwv;
  }

#pragma unroll
  for (int t = 0; t < 2; ++t) {
    int jj = lane + 64 * t;
    float4 hw = *(const float4*)&h1w[jj * 4];
    float y = h1b[jj];
    y = fmaf(hw.x, qv[0], y);
    y = fmaf(hw.y, qv[1], y);
    y = fmaf(hw.z, qv[2], y);
    y = fmaf(hw.w, qv[3], y);
    y = fmaf(bg[jj] * BN_INV, y, bb[jj]);
    ybuf[wv4][jj] = fmaxf(y, 0.f);
  }
  __syncthreads();

#pragma unroll
  for (int t = 0; t < 2; ++t) {
    int k = lane + 64 * t;
    if (k < 100) {
      const float* wr = h2w + k * 128;
      float o = h2b[k];
      const float* yb = ybuf[wv4];
#pragma unroll
      for (int jj = 0; jj < 128; jj += 4) {
        float4 wvv = *(const float4*)&wr[jj];
        o = fmaf(wvv.x, yb[jj + 0], o);
        o = fmaf(wvv.y, yb[jj + 1], o);
        o = fmaf(wvv.z, yb[jj + 2], o);
        o = fmaf(wvv.w, yb[jj + 3], o);
      }
      out[(size_t)b * 100 + k] = o;
    }
  }
}

extern "C" void kernel_launch(void* const* d_in, const int* in_sizes, int n_in,
                              void* d_out, int out_size, void* d_ws,
                              size_t ws_size, hipStream_t stream) {
  const float* x = (const float*)d_in[0];
  const float* c1w = (const float*)d_in[1];
  const float* c1b = (const float*)d_in[2];
  const float* g1 = (const float*)d_in[3];
  const float* be1 = (const float*)d_in[4];
  const float* c2w = (const float*)d_in[5];
  const float* c2b = (const float*)d_in[6];
  const float* g2 = (const float*)d_in[7];
  const float* be2 = (const float*)d_in[8];
  const float* c3w = (const float*)d_in[9];
  const float* c3b = (const float*)d_in[10];
  const float* g3 = (const float*)d_in[11];
  const float* be3 = (const float*)d_in[12];
  const float* fr1w = (const float*)d_in[13];
  const float* fr1b = (const float*)d_in[14];
  const float* fr2w = (const float*)d_in[15];
  const float* fr2b = (const float*)d_in[16];
  const float* qwts = (const float*)d_in[17];
  const float* h1w = (const float*)d_in[18];
  const float* h1b = (const float*)d_in[19];
  const float* bhg = (const float*)d_in[20];
  const float* bhb = (const float*)d_in[21];
  const float* h2w = (const float*)d_in[22];
  const float* h2b = (const float*)d_in[23];
  float* out = (float*)d_out;

  float* ws = (float*)d_ws;
  // layout (float offsets), ~8.6 MB total:
  //   out3bf [0, 1048576)         bf16 [1024,2048]
  //   h1     [1048576, 1572864)   f32  [1024,512]
  //   wfr1   [1572864, 2097152)   bf16 [512,2048]
  //   wp2    [2097152, +9216) | wp3 [2106368, +36864) | scsh [2143232, +384)
  short* out3bf = (short*)ws;
  float* h1 = ws + 1048576;
  short* wfr1 = (short*)(ws + 1572864);
  short* wp2 = (short*)(ws + 2097152);
  short* wp3 = (short*)(ws + 2106368);
  float* scsh = ws + 2143232;

  k_prepack<<<96, 256, 0, stream>>>(c2w, c2b, g2, be2, c3w, c3b, g3, be3, fr1w,
                                    wp2, wp3, scsh, wfr1);
  k_conv123<<<NB, 256, 0, stream>>>(x, c1w, c1b, g1, be1, wp2, wp3, scsh,
                                    out3bf);
  k_fr1m<<<dim3(32, 16), 256, 0, stream>>>(out3bf, wfr1, fr1b, h1);
  k_tail4<<<256, 256, 0, stream>>>(h1, fr2w, fr2b, qwts, h1w, h1b, bhg, bhb,
                                   h2w, h2b, out);
}